// Round 13
// 427.829 us; speedup vs baseline: 1.6285x; 1.0077x over previous
//
#include <hip/hip_runtime.h>
#include <hip/hip_bf16.h>
#include <math.h>

#define TPB 256

constexpr int   B_  = 256;
constexpr int   C_  = 1024;
constexpr int   N_  = 80;
constexpr int   BNr = B_ * N_;                 // 20480 rows for BN / GEMM M
constexpr int   CN  = C_ * N_;                 // 81920
constexpr long  BCN = (long)B_ * C_ * N_;      // 20971520
constexpr int   NN  = N_ * N_;                 // 6400
constexpr int   BNN = B_ * NN;                 // 1638400
constexpr int   ADJP = N_ * 96;                // 7680 padded adj elems
constexpr float EPSf = 1e-5f;

typedef __bf16 bf16x8 __attribute__((ext_vector_type(8)));
typedef float  f32x4  __attribute__((ext_vector_type(4)));

__device__ __forceinline__ float leakyf(float v) { return v >= 0.0f ? v : 0.2f * v; }

__device__ __forceinline__ ushort f2bf(float f) {
  __hip_bfloat16 h = __float2bfloat16(f);
  ushort u; __builtin_memcpy(&u, &h, 2); return u;
}
__device__ __forceinline__ float b2f(ushort u) {
  __hip_bfloat16 h; __builtin_memcpy(&h, &u, 2);
  return __bfloat162float(h);
}

#define GLOBAL_AS __attribute__((address_space(1)))
#define LDS_AS    __attribute__((address_space(3)))
__device__ __forceinline__ void load_lds16(const void* g, void* l) {
  __builtin_amdgcn_global_load_lds((const GLOBAL_AS void*)g, (LDS_AS void*)l, 16, 0, 0);
}

// ---------------------------------------------------------------------------
// K-PREP (merged): blockIdx ranges ->
//   [0,1024)    : Wts[o][c] = bf16(Ws[c][o])   (32x32 tile transpose)
//   [1024,2048) : Wtd[o][c] = bf16(Wd[c][o])
//   [2048,2208) : split Wco (80x2048) -> Wco1t / Wco2t bf16
//   [2208,3232) : Wg -> Wg_bf elementwise
//   [3232,3258) : zero go(20480) + ssum1/ssq1/ssum2/ssq2/gsum/gsq (6144 floats)
//   [3258]      : prep_adj (sadj, adj_bf, lossa=0)
// ---------------------------------------------------------------------------
__global__ __launch_bounds__(256) void k_prep_all(
    const float* __restrict__ Ws, const float* __restrict__ Wd,
    const float* __restrict__ Wco, const float* __restrict__ Wg,
    ushort* __restrict__ Wts, ushort* __restrict__ Wtd,
    ushort* __restrict__ Wco1t, ushort* __restrict__ Wco2t, ushort* __restrict__ Wg_bf,
    float* __restrict__ zbase,
    const float* __restrict__ ap, float* __restrict__ sadj,
    ushort* __restrict__ adj_bf, float* __restrict__ lossa) {
  __shared__ float sh[NN];          // 25.6 KB; doubles as 32x33 transpose tile
  __shared__ float red[TPB];
  __shared__ float sD[N_];
  __shared__ float s_lo, s_hi;
  const int t = threadIdx.x;
  const int blk = blockIdx.x;
  if (blk < 2048) {
    const float* W = (blk < 1024) ? Ws : Wd;
    ushort* Wt = (blk < 1024) ? Wts : Wtd;
    const int bb = blk & 1023;
    const int bx = bb & 31, by = bb >> 5;
    const int tx = t % 32, ty = t / 32;
    const int r0 = by * 32, c0 = bx * 32;
#pragma unroll
    for (int k = 0; k < 4; ++k) sh[(ty + 8 * k) * 33 + tx] = W[(size_t)(r0 + ty + 8 * k) * C_ + c0 + tx];
    __syncthreads();
#pragma unroll
    for (int k = 0; k < 4; ++k) Wt[(size_t)(c0 + ty + 8 * k) * C_ + r0 + tx] = f2bf(sh[tx * 33 + ty + 8 * k]);
  } else if (blk < 2208) {
    const int i4 = ((blk - 2048) * TPB + t) * 4;   // 80*2048 elems
    const int o = i4 >> 11, k = i4 & 2047;
    float4 v = *(const float4*)&Wco[(size_t)o * 2048 + k];
    ushort4 u;
    u.x = f2bf(v.x); u.y = f2bf(v.y); u.z = f2bf(v.z); u.w = f2bf(v.w);
    if (k < C_) *(ushort4*)&Wco1t[(size_t)o * C_ + k] = u;
    else        *(ushort4*)&Wco2t[(size_t)o * C_ + (k - C_)] = u;
  } else if (blk < 3232) {
    const long i4 = ((long)(blk - 2208) * TPB + t) * 4;
    float4 v = *(const float4*)&Wg[i4];
    ushort4 u;
    u.x = f2bf(v.x); u.y = f2bf(v.y); u.z = f2bf(v.z); u.w = f2bf(v.w);
    *(ushort4*)&Wg_bf[i4] = u;
  } else if (blk < 3258) {
    const int i = ((blk - 3232) * TPB + t) * 4;    // 26624 floats
    float4 z = make_float4(0.f, 0.f, 0.f, 0.f);
    *(float4*)&zbase[i] = z;
  } else {
    // ---- prep_adj (single block) ----
    float lo = 3.4e38f, hi = -3.4e38f;
    for (int i = t; i < NN; i += TPB) { float v = ap[i]; sh[i] = v; lo = fminf(lo, v); hi = fmaxf(hi, v); }
    red[t] = lo; __syncthreads();
    for (int o = 128; o > 0; o >>= 1) { if (t < o) red[t] = fminf(red[t], red[t + o]); __syncthreads(); }
    if (t == 0) s_lo = red[0];
    __syncthreads();
    red[t] = hi; __syncthreads();
    for (int o = 128; o > 0; o >>= 1) { if (t < o) red[t] = fmaxf(red[t], red[t + o]); __syncthreads(); }
    if (t == 0) s_hi = red[0];
    __syncthreads();
    const float inv = 1.0f / (s_hi - s_lo);
    for (int i = t; i < NN; i += TPB) { float v = (sh[i] - s_lo) * inv; sh[i] = v; sadj[i] = v; }
    __syncthreads();
    if (t < N_) { float sum = 0.f; for (int m = 0; m < N_; ++m) sum += sh[t * N_ + m]; sD[t] = rsqrtf(sum); }
    if (t == 0) *lossa = 0.0f;
    __syncthreads();
    for (int i = t; i < ADJP; i += TPB) {
      const int n = i / 96, m = i % 96;
      adj_bf[i] = f2bf((m < N_) ? sD[n] * sh[m * N_ + n] * sD[m] : 0.0f);
    }
  }
}

// ---------------------------------------------------------------------------
// K-TADJ: per-b tadj build + fused adjacency loss.  One block per b.
// ---------------------------------------------------------------------------
__global__ __launch_bounds__(256) void k_tadj(const float* __restrict__ dadj,
                                              const float* __restrict__ bmin,
                                              const float* __restrict__ bmax,
                                              const float* __restrict__ sadj,
                                              const float* __restrict__ out1,
                                              ushort* __restrict__ tadj,
                                              float* __restrict__ lossa) {
  __shared__ float sF[NN];
  __shared__ float sD[N_];
  __shared__ float rl[TPB], rh[TPB];
  __shared__ float s_lo, s_inv;
  const int t = threadIdx.x;
  const int b = blockIdx.x;
  rl[t] = (t < 160) ? bmin[t] : 3.4e38f;
  rh[t] = (t < 160) ? bmax[t] : -3.4e38f;
  __syncthreads();
  for (int o = 128; o > 0; o >>= 1) {
    if (t < o) { rl[t] = fminf(rl[t], rl[t + o]); rh[t] = fmaxf(rh[t], rh[t + o]); }
    __syncthreads();
  }
  if (t == 0) { s_lo = rl[0]; s_inv = 1.0f / (rh[0] - rl[0]); }
  __syncthreads();
  const float lo = s_lo, inv = s_inv;
  const float* db = dadj + (size_t)b * NN;
  for (int i = t; i < NN / 4; i += TPB) {
    float4 v = *(const float4*)&db[i * 4];
    v.x = (v.x - lo) * inv; v.y = (v.y - lo) * inv;
    v.z = (v.z - lo) * inv; v.w = (v.w - lo) * inv;
    *(float4*)&sF[i * 4] = v;
  }
  __syncthreads();
  if (t < N_) { float s = 0.f; for (int m = 0; m < N_; ++m) s += sF[t * N_ + m]; sD[t] = rsqrtf(s); }
  __syncthreads();
  ushort* tb = tadj + (size_t)b * ADJP;
  for (int i = t; i < ADJP; i += TPB) {
    const int n = i / 96, m = i % 96;
    tb[i] = f2bf((m < N_) ? sF[m * N_ + n] * sD[n] * sD[m] : 0.0f);
  }
  // ---- fused loss ----
  const float* o1 = out1 + b * N_;
  float p2 = 0.f;
  for (int i = t; i < NN; i += TPB) { const float d = sF[i] - sadj[i]; p2 += d * d; }
  float p1 = 0.f;
  if (t < N_) {
    float a = 0.f;
    for (int n = 0; n < N_; ++n) a += o1[n] * sF[n * N_ + t];
    const float d = o1[t] - a * (1.0f / N_);
    p1 = d * d;
  }
  rl[t] = p2; rh[t] = p1;
  __syncthreads();
  for (int o = 128; o > 0; o >>= 1) {
    if (t < o) { rl[t] += rl[t + o]; rh[t] += rh[t + o]; }
    __syncthreads();
  }
  if (t == 0) atomicAdd(lossa, sqrtf(rl[0]) + sqrtf(rh[0]));
}

// ---------------------------------------------------------------------------
// K-FOLD (barrier-free streaming, ALL loads hoisted before any MFMA):
//   out[(b*80+n)*1024 + c] (bf16, B,N,C) = sum_m adj[n,m] * X[b,c,m]
// Verified r12 (BANK_CONFLICT 0, dropped out of top-5).
// ---------------------------------------------------------------------------
template <int MODE>
__global__ __launch_bounds__(256) void k_fold(const float* __restrict__ Xf32,
                                              const ushort* __restrict__ Xbf,
                                              const ushort* __restrict__ adjb,
                                              ushort* __restrict__ outp) {
  const int t = threadIdx.x;
  const int b  = blockIdx.x >> 3;
  const int c0 = (blockIdx.x & 7) * 128;
  const int lane = t & 63, wid = t >> 6;
  const int l16 = lane & 15, lq = lane >> 4;
  const ushort* ab = adjb + (MODE ? (size_t)b * ADJP : 0);

  bf16x8 b5[3][5], a2[3][2];

  // ---- load burst: all B frags (L2-resident) + all A frags (global) ----
#pragma unroll
  for (int kk = 0; kk < 3; ++kk) {
    const int mf = kk * 32 + lq * 8;
#pragma unroll
    for (int j = 0; j < 5; ++j)
      b5[kk][j] = *(const bf16x8*)&ab[(j * 16 + l16) * 96 + mf];
  }
#pragma unroll
  for (int kk = 0; kk < 3; ++kk) {
    const int mf = kk * 32 + lq * 8;
#pragma unroll
    for (int i = 0; i < 2; ++i) {
      const int row = wid * 32 + i * 16 + l16;
      if (mf >= N_) {
        union { bf16x8 v; uint4 u; } z; z.u = make_uint4(0, 0, 0, 0);
        a2[kk][i] = z.v;
      } else if (MODE == 0) {
        const float* src = Xf32 + ((size_t)b * C_ + c0 + row) * N_ + mf;
        float4 v0 = *(const float4*)src;
        float4 v1 = *(const float4*)(src + 4);
        union { bf16x8 v; ushort u[8]; } tmp;
        tmp.u[0] = f2bf(v0.x); tmp.u[1] = f2bf(v0.y); tmp.u[2] = f2bf(v0.z); tmp.u[3] = f2bf(v0.w);
        tmp.u[4] = f2bf(v1.x); tmp.u[5] = f2bf(v1.y); tmp.u[6] = f2bf(v1.z); tmp.u[7] = f2bf(v1.w);
        a2[kk][i] = tmp.v;
      } else {
        a2[kk][i] = *(const bf16x8*)&Xbf[((size_t)b * C_ + c0 + row) * N_ + mf];
      }
    }
  }

  // ---- compute: 30 MFMAs on fully-resident operands ----
  f32x4 acc[2][5];
#pragma unroll
  for (int i = 0; i < 2; ++i)
#pragma unroll
    for (int j = 0; j < 5; ++j) { f32x4 z = {0.f, 0.f, 0.f, 0.f}; acc[i][j] = z; }
#pragma unroll
  for (int kk = 0; kk < 3; ++kk)
#pragma unroll
    for (int i = 0; i < 2; ++i)
#pragma unroll
      for (int j = 0; j < 5; ++j)
        acc[i][j] = __builtin_amdgcn_mfma_f32_16x16x32_bf16(a2[kk][i], b5[kk][j], acc[i][j], 0, 0, 0);

  // ---- epilogue: D[row=c_local (lq*4+reg)][col=n (l16)] -> (B,N,C) ushort4 ----
  ushort* ob = outp + (size_t)b * CN;
#pragma unroll
  for (int i = 0; i < 2; ++i) {
    const int c = c0 + wid * 32 + i * 16 + lq * 4;
#pragma unroll
    for (int j = 0; j < 5; ++j) {
      const int n = j * 16 + l16;
      ushort4 u;
      u.x = f2bf(acc[i][j][0]); u.y = f2bf(acc[i][j][1]);
      u.z = f2bf(acc[i][j][2]); u.w = f2bf(acc[i][j][3]);
      *(ushort4*)&ob[(size_t)n * C_ + c] = u;
    }
  }
}

// ---------------------------------------------------------------------------
// K2: 160x128x64 dbuf MFMA GEMM, 2 blocks/CU, ONE barrier per K-tile.
// Hazard analysis for the single-sync structure:
//  (a) staging buffer P occurs after the __syncthreads that followed all
//      waves' (lgkm-completed) reads of P in the previous tile;
//  (b) reads of P occur after the __syncthreads whose implicit vmcnt(0)
//      drained every wave's stage loads of P.
// Both phases of a tile fused into one scheduling region (18 ds_reads +
// 40 MFMA) so the compiler pipelines freely; compiler inserts lgkm waits
// via register data deps.  + fused per-channel BN stats.
// ---------------------------------------------------------------------------
__global__ __launch_bounds__(256, 2) void k_gemm_160(const ushort* __restrict__ A,
                                                     const ushort* __restrict__ Bt,
                                                     void* __restrict__ outp, int out_bf,
                                                     float* __restrict__ bnsum,
                                                     float* __restrict__ bnsq) {
  __shared__ ushort sA[2][160 * 64];   // 2 x 20 KB
  __shared__ ushort sB[2][128 * 64];   // 2 x 16 KB
  const int t = threadIdx.x;
  const int lane = t & 63, wid = t >> 6;       // 4 waves
  const int wm = wid >> 1, wn = wid & 1;       // 2M x 2N
  const int l16 = lane & 15, lq = lane >> 4;

  // XCD-chunked swizzle: 1024 blocks; each XCD: tm in [xcd*16, xcd*16+16), tn 0..7.
  const int lin = blockIdx.x;
  const int xcd = lin & 7, bi = lin >> 3;      // bi in 0..127
  const int tm = xcd * 16 + (bi >> 3);
  const int tn = bi & 7;
  const int m0 = tm * 160, o0 = tn * 128;

  const int srow = t >> 3;                           // 0..31 (32 rows per call)
  const int sswz = ((t & 7) ^ ((t >> 3) & 7)) * 8;   // pre-swizzled source slot

  f32x4 acc[5][4];
#pragma unroll
  for (int i = 0; i < 5; ++i)
#pragma unroll
    for (int j = 0; j < 4; ++j) { f32x4 z = {0.f, 0.f, 0.f, 0.f}; acc[i][j] = z; }

#define STA(PAR, ROWB, KT) load_lds16(A  + (size_t)(m0 + (ROWB) + srow) * C_ + (KT) * 64 + sswz, \
                                      &sA[PAR][((ROWB) + (wid << 3)) * 64])
#define STB(PAR, ROWB, KT) load_lds16(Bt + (size_t)(o0 + (ROWB) + srow) * C_ + (KT) * 64 + sswz, \
                                      &sB[PAR][((ROWB) + (wid << 3)) * 64])
#define STAGE_T(PAR, KT) { STA(PAR, 0, KT); STA(PAR, 32, KT); STA(PAR, 64, KT); \
                           STA(PAR, 96, KT); STA(PAR, 128, KT); \
                           STB(PAR, 0, KT); STB(PAR, 32, KT); STB(PAR, 64, KT); STB(PAR, 96, KT); }

#define COMP(PAR)                                                                         \
  {                                                                                       \
    bf16x8 af0[5], bf0[4], af1[5], bf1[4];                                                \
    _Pragma("unroll") for (int fi = 0; fi < 5; ++fi)                                      \
      af0[fi] = *(const bf16x8*)&sA[PAR][(wm * 80 + fi * 16 + l16) * 64 +                 \
                                         ((lq) ^ (l16 & 7)) * 8];                         \
    _Pragma("unroll") for (int gi = 0; gi < 4; ++gi)                                      \
      bf0[gi] = *(const bf16x8*)&sB[PAR][(wn * 64 + gi * 16 + l16) * 64 +                 \
                                         ((lq) ^ (l16 & 7)) * 8];                         \
    _Pragma("unroll") for (int fi = 0; fi < 5; ++fi)                                      \
      af1[fi] = *(const bf16x8*)&sA[PAR][(wm * 80 + fi * 16 + l16) * 64 +                 \
                                         ((4 + lq) ^ (l16 & 7)) * 8];                     \
    _Pragma("unroll") for (int gi = 0; gi < 4; ++gi)                                      \
      bf1[gi] = *(const bf16x8*)&sB[PAR][(wn * 64 + gi * 16 + l16) * 64 +                 \
                                         ((4 + lq) ^ (l16 & 7)) * 8];                     \
    __builtin_amdgcn_s_setprio(1);                                                        \
    _Pragma("unroll") for (int fi = 0; fi < 5; ++fi)                                      \
      _Pragma("unroll") for (int gi = 0; gi < 4; ++gi)                                    \
        acc[fi][gi] = __builtin_amdgcn_mfma_f32_16x16x32_bf16(af0[fi], bf0[gi],           \
                                                              acc[fi][gi], 0, 0, 0);      \
    _Pragma("unroll") for (int fi = 0; fi < 5; ++fi)                                      \
      _Pragma("unroll") for (int gi = 0; gi < 4; ++gi)                                    \
        acc[fi][gi] = __builtin_amdgcn_mfma_f32_16x16x32_bf16(af1[fi], bf1[gi],           \
                                                              acc[fi][gi], 0, 0, 0);      \
    __builtin_amdgcn_s_setprio(0);                                                        \
  }

  // prologue: stage T0 into par0; __syncthreads drains vmcnt + barriers.
  STAGE_T(0, 0);
  __syncthreads();

  for (int i = 0; i < 8; ++i) {
    // tile 2i in par0; stage T(2i+1) -> par1
    STAGE_T(1, 2 * i + 1);
    COMP(0);
    __syncthreads();                 // drains par1 stage; retires par0 reads
    // tile 2i+1 in par1; stage T(2i+2) -> par0
    if (i < 7) { STAGE_T(0, 2 * i + 2); }
    COMP(1);
    if (i < 7) __syncthreads();      // drains par0 stage; retires par1 reads
  }

  // epilogue: row = lq*4+reg -> m; col = l16 -> o. (B,C,N) store, 4 consecutive n.
#pragma unroll
  for (int fi = 0; fi < 5; ++fi) {
    const int mg = m0 + wm * 80 + fi * 16 + lq * 4;
    const int b  = mg / 80;
    const int n0 = mg - b * 80;
#pragma unroll
    for (int gi = 0; gi < 4; ++gi) {
      const int og = o0 + wn * 64 + gi * 16 + l16;
      const size_t off = (size_t)b * CN + (size_t)og * N_ + n0;
      if (out_bf) {
        ushort4 u;
        u.x = f2bf(acc[fi][gi][0]); u.y = f2bf(acc[fi][gi][1]);
        u.z = f2bf(acc[fi][gi][2]); u.w = f2bf(acc[fi][gi][3]);
        *(ushort4*)((ushort*)outp + off) = u;
      } else {
        *(f32x4*)((float*)outp + off) = acc[fi][gi];
      }
    }
  }

  // ---- fused BN partial stats (sA[0] retired at the i=7 mid-tile barrier) ----
  {
    float* redS = (float*)&sA[0][0];           // [128][8]
    float* redQ = redS + 1024;                 // [128][8]
    const int slot = wm * 4 + lq;              // 0..7
#pragma unroll
    for (int gi = 0; gi < 4; ++gi) {
      float s = 0.f, q = 0.f;
#pragma unroll
      for (int fi = 0; fi < 5; ++fi)
#pragma unroll
        for (int r = 0; r < 4; ++r) { const float v = acc[fi][gi][r]; s += v; q += v * v; }
      const int ol = wn * 64 + gi * 16 + l16;  // 0..127, unique per (wn,gi,l16)
      redS[ol * 8 + slot] = s;
      redQ[ol * 8 + slot] = q;
    }
    __syncthreads();
    if (t < 128) {
      float s = 0.f, q = 0.f;
#pragma unroll
      for (int k = 0; k < 8; ++k) { s += redS[t * 8 + k]; q += redQ[t * 8 + k]; }
      atomicAdd(&bnsum[o0 + t], s);
      atomicAdd(&bnsq[o0 + t], q);
    }
  }
#undef STA
#undef STB
#undef STAGE_T
#undef COMP
}

// ---------------------------------------------------------------------------
// K2b: dadj MFMA GEMM. A: x2t bf16 (M=20480, K=1024). Bw: Wco2t bf16 (80,1024).
// dadj[b,o,n] = go[b,o] + bco[o] + sum_k A[m=(b,n)][k]*Bw[o][k].
// Fused per-block min/max -> bmin/bmax[160].
// ---------------------------------------------------------------------------
__global__ __launch_bounds__(256) void k_dadj_mfma(const ushort* __restrict__ A,
                                                   const ushort* __restrict__ Bw,
                                                   const float* __restrict__ go,
                                                   const float* __restrict__ bco,
                                                   float* __restrict__ dadj,
                                                   float* __restrict__ bmin,
                                                   float* __restrict__ bmax) {
  __shared__ ushort smA[128 * 32];
  __shared__ ushort smB[80 * 32];
  const int t = threadIdx.x;
  const int lane = t & 63, wid = t >> 6;
  const int m0 = blockIdx.x * 128;
  const int rto = t >> 2, ch = t & 3;
  const size_t gA0 = (size_t)(m0 + rto) * C_ + (size_t)ch * 8;
  ushort* ldsA = smA + wid * 512;
  const int l16 = lane & 15, lq = lane >> 4;
  const int wrow = wid * 32;
  f32x4 zero = {0.f, 0.f, 0.f, 0.f};
  f32x4 acc[2][5];
#pragma unroll
  for (int i = 0; i < 2; ++i)
#pragma unroll
    for (int j = 0; j < 5; ++j) acc[i][j] = zero;
  for (int k0 = 0; k0 < C_; k0 += 32) {
    load_lds16(A + gA0 + k0,            ldsA);
    load_lds16(A + gA0 + 64 * C_ + k0,  ldsA + 2048);
    {
      const int idx = t;                               // 320 chunks of 16B
      uint4 v = *(const uint4*)&Bw[(size_t)(idx >> 2) * C_ + k0 + (idx & 3) * 8];
      *(uint4*)&smB[idx * 8] = v;
      if (t < 64) {
        const int idx2 = 256 + t;
        uint4 v2 = *(const uint4*)&Bw[(size_t)(idx2 >> 2) * C_ + k0 + (idx2 & 3) * 8];
        *(uint4*)&smB[idx2 * 8] = v2;
      }
    }
    __syncthreads();
    bf16x8 af[2], bfr[5];
#pragma unroll
    for (int i = 0; i < 2; ++i) af[i]  = *(const bf16x8*)&smA[(wrow + i * 16 + l16) * 32 + lq * 8];
#pragma unroll
    for (int j = 0; j < 5; ++j) bfr[j] = *(const bf16x8*)&smB[(j * 16 + l16) * 32 + lq * 8];
#pragma unroll
    for (int i = 0; i < 2; ++i)
#pragma unroll
      for (int j = 0; j < 5; ++j)
        acc[i][j] = __builtin_amdgcn_mfma_f32_16x16x32_bf16(af[i], bfr[j], acc[i][j], 0, 0, 0);
    __syncthreads();
  }
  float vlo = 3.4e38f, vhi = -3.4e38f;
#pragma unroll
  for (int i = 0; i < 2; ++i) {
    const int mg = m0 + wrow + i * 16 + lq * 4;
    const int b  = mg / 80;
    const int n0 = mg - b * 80;
    const float* gob = go + b * N_;
#pragma unroll
    for (int j = 0; j < 5; ++j) {
      const int o = j * 16 + l16;
      const float g = gob[o] + bco[o];
      f32x4 v = acc[i][j];
      v[0] += g; v[1] += g; v[2] += g; v[3] += g;
      vlo = fminf(vlo, fminf(fminf(v[0], v[1]), fminf(v[2], v[3])));
      vhi = fmaxf(vhi, fmaxf(fmaxf(v[0], v[1]), fmaxf(v[2], v[3])));
      *(f32x4*)&dadj[(size_t)b * NN + (size_t)o * N_ + n0] = v;
    }
  }
  // block min/max reduce (reuse smA as float scratch; all LDS reads done)
  float* red = (float*)smA;
  red[t] = vlo; red[TPB + t] = vhi;
  __syncthreads();
  for (int o = 128; o > 0; o >>= 1) {
    if (t < o) {
      red[t] = fminf(red[t], red[t + o]);
      red[TPB + t] = fmaxf(red[TPB + t], red[TPB + t + o]);
    }
    __syncthreads();
  }
  if (t == 0) { bmin[blockIdx.x] = red[0]; bmax[blockIdx.x] = red[TPB]; }
}

// ---------------------------------------------------------------------------
// K2c: glb1 MFMA GEMM. A: glb0_bf (256 x 1024). Bw: Wg_bf (1024 x 1024, K-contig).
// + fused per-channel stats (sum/sumsq of glb1 incl. bias) -> gsum/gsq atomics.
// ---------------------------------------------------------------------------
__global__ __launch_bounds__(256) void k_glb_mfma(const ushort* __restrict__ A,
                                                  const ushort* __restrict__ Bw,
                                                  const float* __restrict__ bias,
                                                  float* __restrict__ outp,
                                                  float* __restrict__ gsum,
                                                  float* __restrict__ gsq) {
  __shared__ ushort smA[2][64 * 32];
  __shared__ ushort smB[2][64 * 32];
  const int t = threadIdx.x;
  const int lane = t & 63, wid = t >> 6;
  const int o0 = blockIdx.x * 64, m0 = blockIdx.y * 64;
  const int rto = t >> 2, ch = t & 3;
  const size_t gA0 = (size_t)(m0 + rto) * C_ + (size_t)ch * 8;
  const size_t gB0 = (size_t)(o0 + rto) * C_ + (size_t)ch * 8;
  const int l16 = lane & 15, lq = lane >> 4;
  const int wm = wid & 1, wn = wid >> 1;
  f32x4 zero = {0.f, 0.f, 0.f, 0.f};
  f32x4 acc[2][2];
#pragma unroll
  for (int i = 0; i < 2; ++i)
#pragma unroll
    for (int j = 0; j < 2; ++j) acc[i][j] = zero;
  for (int k0 = 0; k0 < C_; k0 += 64) {
    load_lds16(A  + gA0 + k0,       smA[0] + wid * 512);
    load_lds16(A  + gA0 + k0 + 32,  smA[1] + wid * 512);
    load_lds16(Bw + gB0 + k0,       smB[0] + wid * 512);
    load_lds16(Bw + gB0 + k0 + 32,  smB[1] + wid * 512);
    __syncthreads();
#pragma unroll
    for (int h = 0; h < 2; ++h) {
      bf16x8 af[2], bfr[2];
#pragma unroll
      for (int i = 0; i < 2; ++i) af[i]  = *(const bf16x8*)&smA[h][(wm * 32 + i * 16 + l16) * 32 + lq * 8];
#pragma unroll
      for (int j = 0; j < 2; ++j) bfr[j] = *(const bf16x8*)&smB[h][(wn * 32 + j * 16 + l16) * 32 + lq * 8];
#pragma unroll
      for (int i = 0; i < 2; ++i)
#pragma unroll
        for (int j = 0; j < 2; ++j)
          acc[i][j] = __builtin_amdgcn_mfma_f32_16x16x32_bf16(af[i], bfr[j], acc[i][j], 0, 0, 0);
    }
    __syncthreads();
  }
  float ssv[2] = {0.f, 0.f}, sqv[2] = {0.f, 0.f};
#pragma unroll
  for (int i = 0; i < 2; ++i) {
    const int mg = m0 + wm * 32 + i * 16 + lq * 4;
#pragma unroll
    for (int j = 0; j < 2; ++j) {
      const int og = o0 + wn * 32 + j * 16 + l16;
      const float bs = bias[og];
      f32x4 v = acc[i][j];
#pragma unroll
      for (int r = 0; r < 4; ++r) {
        const float val = v[r] + bs;
        outp[(size_t)(mg + r) * C_ + og] = val;
        ssv[j] += val; sqv[j] += val * val;
      }
    }
  }
  // stats reduce: [64 og_local][8 slots] in smA (free after last sync)
  {
    float* redS = (float*)&smA[0][0];
    float* redQ = redS + 512;
    const int slot = wm * 4 + lq;
#pragma unroll
    for (int j = 0; j < 2; ++j) {
      const int ol = wn * 32 + j * 16 + l16;   // 0..63
      redS[ol * 8 + slot] = ssv[j];
      redQ[ol * 8 + slot] = sqv[j];
    }
    __syncthreads();
    if (t < 64) {
      float s = 0.f, q = 0.f;
#pragma unroll
      for (int k = 0; k < 8; ++k) { s += redS[t * 8 + k]; q += redQ[t * 8 + k]; }
      atomicAdd(&gsum[o0 + t], s);
      atomicAdd(&gsq[o0 + t], q);
    }
  }
}

// ---------------------------------------------------------------------------
// K2d: go MFMA GEMM, split-K x8, BN+leaky applied inline from gsum/gsq while
// reg-staging A from fp32 glb1 (replaces k_bng + glbf buffer).
// ---------------------------------------------------------------------------
__global__ __launch_bounds__(256) void k_go_mfma(const float* __restrict__ glb1,
                                                 const ushort* __restrict__ Bw,
                                                 const float* __restrict__ gsum,
                                                 const float* __restrict__ gsq,
                                                 const float* __restrict__ gg,
                                                 const float* __restrict__ gb,
                                                 float* __restrict__ go) {
  __shared__ ushort smA[128 * 32];
  __shared__ ushort smB[80 * 32];
  __shared__ float pgm[C_], pmu[C_], pgb[C_];
  const int t = threadIdx.x;
  const int lane = t & 63, wid = t >> 6;
  const int kbase = blockIdx.x * 128;
  const int m0 = blockIdx.y * 128;
  const int rto = t >> 2, ch = t & 3;
  const int l16 = lane & 15, lq = lane >> 4;
  const int wrow = wid * 32;
  for (int c = t; c < C_; c += TPB) {
    const float mu = gsum[c] * (1.0f / B_);
    const float var = gsq[c] * (1.0f / B_) - mu * mu;
    pgm[c] = gg[c] * rsqrtf(var + EPSf); pmu[c] = mu; pgb[c] = gb[c];
  }
  __syncthreads();
  f32x4 zero = {0.f, 0.f, 0.f, 0.f};
  f32x4 acc[2][5];
#pragma unroll
  for (int i = 0; i < 2; ++i)
#pragma unroll
    for (int j = 0; j < 5; ++j) acc[i][j] = zero;
  for (int kk0 = 0; kk0 < 128; kk0 += 32) {
    const int k0 = kbase + kk0;
    // A: rows m0+h*64+rto, cols k0+ch*8..+8; BN+leaky+bf16 in registers
#pragma unroll
    for (int h = 0; h < 2; ++h) {
      const float* src = &glb1[(size_t)(m0 + h * 64 + rto) * C_ + k0 + ch * 8];
      float4 a0 = *(const float4*)src;
      float4 a1 = *(const float4*)(src + 4);
      float av[8] = {a0.x, a0.y, a0.z, a0.w, a1.x, a1.y, a1.z, a1.w};
      ushort4 u0, u1;
      const int cb = k0 + ch * 8;
      u0.x = f2bf(leakyf(pgm[cb+0]*(av[0]-pmu[cb+0])+pgb[cb+0]));
      u0.y = f2bf(leakyf(pgm[cb+1]*(av[1]-pmu[cb+1])+pgb[cb+1]));
      u0.z = f2bf(leakyf(pgm[cb+2]*(av[2]-pmu[cb+2])+pgb[cb+2]));
      u0.w = f2bf(leakyf(pgm[cb+3]*(av[3]-pmu[cb+3])+pgb[cb+3]));
      u1.x = f2bf(leakyf(pgm[cb+4]*(av[4]-pmu[cb+4])+pgb[cb+4]));
      u1.y = f2bf(leakyf(pgm[cb+5]*(av[5]-pmu[cb+5])+pgb[cb+5]));
      u1.z = f2bf(leakyf(pgm[cb+6]*(av[6]-pmu[cb+6])+pgb[cb+6]));
      u1.w = f2bf(leakyf(pgm[cb+7]*(av[7]-pmu[cb+7])+pgb[cb+7]));
      *(ushort4*)&smA[h * 2048 + t * 8]     = u0;
      *(ushort4*)&smA[h * 2048 + t * 8 + 4] = u1;
    }
    {
      const int idx = t;
      uint4 v = *(const uint4*)&Bw[(size_t)(idx >> 2) * C_ + k0 + (idx & 3) * 8];
      *(uint4*)&smB[idx * 8] = v;
      if (t < 64) {
        const int idx2 = 256 + t;
        uint4 v2 = *(const uint4*)&Bw[(size_t)(idx2 >> 2) * C_ + k0 + (idx2 & 3) * 8];
        *(uint4*)&smB[idx2 * 8] = v2;
      }
    }
    __syncthreads();
    bf16x8 af[2], bfr[5];
#pragma unroll
    for (int i = 0; i < 2; ++i) af[i]  = *(const bf16x8*)&smA[(wrow + i * 16 + l16) * 32 + lq * 8];
#pragma unroll
    for (int j = 0; j < 5; ++j) bfr[j] = *(const bf16x8*)&smB[(j * 16 + l16) * 32 + lq * 8];
#pragma unroll
    for (int i = 0; i < 2; ++i)
#pragma unroll
      for (int j = 0; j < 5; ++j)
        acc[i][j] = __builtin_amdgcn_mfma_f32_16x16x32_bf16(af[i], bfr[j], acc[i][j], 0, 0, 0);
    __syncthreads();
  }
#pragma unroll
  for (int i = 0; i < 2; ++i) {
    const int mg = m0 + wrow + i * 16 + lq * 4;
#pragma unroll
    for (int j = 0; j < 5; ++j) {
      const int o = j * 16 + l16;
#pragma unroll
      for (int r = 0; r < 4; ++r)
        atomicAdd(&go[(size_t)(mg + r) * N_ + o], acc[i][j][r]);
    }
  }
}

// ---------------------------------------------------------------------------
// K4f: fused x2 = x + leaky(bn(hT)) ; bf16 x2 written IN PLACE over hT ;
// x2t transpose (bf16, B,N,C) ; glb0 mean. BN stats from fused gemm sums.
// ---------------------------------------------------------------------------
__global__ __launch_bounds__(256) void k_x2_fused(
    const float* __restrict__ x, ushort* __restrict__ hx,
    const float* __restrict__ g, const float* __restrict__ be,
    const float* __restrict__ ssum, const float* __restrict__ ssq,
    ushort* __restrict__ x2t, ushort* __restrict__ glb0b) {
  __shared__ float s[64][85];
  __shared__ float pg[64], pm[64], pb[64];
  const int t = threadIdx.x;
  const long row0 = (long)blockIdx.x * 64;     // row = b*C + c
  const int b = (int)(row0 >> 10), c0 = (int)(row0 & 1023);
  if (t < 64) {
    const int c = c0 + t;
    const float mu = ssum[c] * (1.0f / BNr);
    const float var = ssq[c] * (1.0f / BNr) - mu * mu;
    const float rstd = rsqrtf(var + EPSf);
    pg[t] = g[c] * rstd; pm[t] = mu; pb[t] = be[c];
  }
  __syncthreads();
  const float* xb = x  + row0 * N_;
  ushort*      hb = hx + row0 * N_;
  for (int i4 = t; i4 < (64 * N_) / 4; i4 += TPB) {
    const int e = i4 * 4, r = e / N_, n = e % N_;
    float4 xv = *(const float4*)&xb[e];
    ushort4 hu = *(const ushort4*)&hb[e];
    const float gm = pg[r], m = pm[r], bb = pb[r];
    float4 o;
    o.x = xv.x + leakyf(gm * (b2f(hu.x) - m) + bb);
    o.y = xv.y + leakyf(gm * (b2f(hu.y) - m) + bb);
    o.z = xv.z + leakyf(gm * (b2f(hu.z) - m) + bb);
    o.w = xv.w + leakyf(gm * (b2f(hu.w) - m) + bb);
    *(float4*)&s[r][n] = o;
    ushort4 ou;
    ou.x = f2bf(o.x); ou.y = f2bf(o.y); ou.z = f2bf(o.z); ou.w = f2bf(o.w);
    *(ushort4*)&hb[e] = ou;                     // in-place bf16 x2 (hT dead)
  }
  __syncthreads();
  // transpose to (B,N,C) bf16
  const int tx = t % 16, ty = t / 16;
  ushort* tb = x2t + (size_t)b * CN + c0 + tx * 4;
#pragma unroll
  for (int u = 0; u < 5; ++u) {
    const int n = ty + 16 * u;
    ushort4 v;
    v.x = f2bf(s[tx * 4 + 0][n]); v.y = f2bf(s[tx * 4 + 1][n]);
    v.z = f2bf(s[tx * 4 + 2][n]); v.w = f2bf(s[tx * 4 + 3][n]);
    *(ushort4*)&tb[(size_t)n * C_] = v;
  }
  // glb0 mean over n — 4 threads per c-row, shfl-reduce the quad
  {
    const int r = t >> 2, q = t & 3;           // r in 0..63
    float sacc = 0.f;
    for (int n = q; n < N_; n += 4) sacc += s[r][n];
    sacc += __shfl_down(sacc, 1);
    sacc += __shfl_down(sacc, 2);
    if (q == 0) glb0b[(size_t)b * C_ + c0 + r] = f2bf(sacc * (1.0f / N_));
  }
}

// ---------------------------------------------------------------------------
// K14: final BN + leaky: reads h2 bf16 (B,C,N) + fused gemm sums,
// writes fp32 out + loss scalar.
// ---------------------------------------------------------------------------
__global__ void k_final(const ushort* __restrict__ h2, float* __restrict__ outp,
                        const float* __restrict__ g, const float* __restrict__ be,
                        const float* __restrict__ ssum, const float* __restrict__ ssq,
                        const float* __restrict__ lossa) {
  const long i = ((long)blockIdx.x * TPB + threadIdx.x) * 4;
  const int c = (int)((i / N_) % C_);
  ushort4 hu = *(const ushort4*)&h2[i];
  const float mu = ssum[c] * (1.0f / BNr);
  const float rstd = rsqrtf(ssq[c] * (1.0f / BNr) - mu * mu + EPSf);
  const float gm = g[c] * rstd, bb = be[c];
  float4 v;
  v.x = leakyf(gm * (b2f(hu.x) - mu) + bb);
  v.y = leakyf(gm * (b2f(hu.y) - mu) + bb);
  v.z = leakyf(gm * (b2f(hu.z) - mu) + bb);
  v.w = leakyf(gm * (b2f(hu.w) - mu) + bb);
  *(float4*)&outp[i] = v;
  if (blockIdx.x == 0 && threadIdx.x == 0) outp[BCN] = *lossa;
}

// ---------------------------------------------------------------------------
extern "C" void kernel_launch(void* const* d_in, const int* in_sizes, int n_in,
                              void* d_out, int out_size, void* d_ws, size_t ws_size,
                              hipStream_t stream) {
  const float* x    = (const float*)d_in[0];
  const float* out1 = (const float*)d_in[1];
  const float* ap   = (const float*)d_in[2];
  const float* Ws   = (const float*)d_in[3];
  const float* Wd   = (const float*)d_in[4];
  const float* Wg   = (const float*)d_in[5];
  const float* bg   = (const float*)d_in[6];
  const float* Wco  = (const float*)d_in[7];
  const float* bco  = (const float*)d_in[8];
  const float* bn_g  = (const float*)d_in[9];
  const float* bn_b  = (const float*)d_in[10];
  const float* bng_g = (const float*)d_in[11];
  const float* bng_b = (const float*)d_in[12];
  float* out = (float*)d_out;

  float* w = (float*)d_ws;
  float* sadj  = w;                    // 6400
  float* dadj  = sadj + NN;            // 1638400
  float* glb0  = dadj + BNN;           // 262144 (used as bf16 ushorts)
  float* glb1  = glb0 + B_ * C_;       // 262144
  float* go    = glb1 + B_ * C_;       // 20480 -- start of contiguous zero region
  float* ssum1 = go + BNr;             // 1024
  float* ssq1  = ssum1 + C_;           // 1024
  float* ssum2 = ssq1 + C_;            // 1024
  float* ssq2  = ssum2 + C_;           // 1024
  float* gsum  = ssq2 + C_;            // 1024
  float* gsq   = gsum + C_;            // 1024 -- end of zero region (26624 floats)
  float* bmin  = gsq + C_;             // 512 (160 used)
  float* bmax  = bmin + 512;           // 512 (160 used)
  float* lossa = bmax + 512;           // 1
  ushort* ub   = (ushort*)(((uintptr_t)(lossa + 1) + 255) & ~(uintptr_t)255);
  ushort* xa_bf  = ub;                    // BCN bf16 (B,N,C): fold out / x2t / fold2 out
  ushort* hT_bf  = xa_bf + BCN;           // BCN bf16 (B,C,N): h -> x2bf (in-place) -> h2
  ushort* Wts    = hT_bf + BCN;           // 1M bf16 (O,C)
  ushort* Wtd    = Wts + (size_t)C_ * C_; // 1M bf16 (O,C)
  ushort* Wco2t  = Wtd + (size_t)C_ * C_; // 80K bf16 (80,1024)
  ushort* adj_bf = Wco2t + (size_t)N_ * C_; // 80x96 bf16 prepadded
  ushort* tadj_bf = adj_bf + ADJP;        // B x 80x96 bf16 (3.93 MB)
  // bf16 aliases in regions dead at time of use:
  ushort* Wg_bf   = (ushort*)dadj;                      // 1M ushorts; dadj written later
  ushort* Wco1t   = (ushort*)dadj + (size_t)C_ * C_;    // 80K ushorts, same region
  ushort* glb0_bf = (ushort*)glb0;
  ushort* x2t_bf  = xa_bf;                              // xa dead after GEMM#1; x2t dead before fold#2

  // ---- prep (single merged launch: transposes, converts, zeroes, prep_adj) ----
  k_prep_all<<<3259, TPB, 0, stream>>>(Ws, Wd, Wco, Wg, Wts, Wtd, Wco1t, Wco2t, Wg_bf,
                                       go, ap, sadj, adj_bf, lossa);

  // ---- static GCN ----
  k_fold<0><<<B_ * 8, TPB, 0, stream>>>(x, hT_bf, adj_bf, xa_bf);
  k_gemm_160<<<1024, TPB, 0, stream>>>(xa_bf, Wts, hT_bf, 1, ssum1, ssq1);
  k_x2_fused<<<(B_ * C_) / 64, TPB, 0, stream>>>(x, hT_bf, bn_g, bn_b, ssum1, ssq1,
                                                 x2t_bf, glb0_bf);

  // ---- dynamic graph construction ----
  k_glb_mfma<<<dim3(C_ / 64, B_ / 64), TPB, 0, stream>>>(glb0_bf, Wg_bf, bg, glb1, gsum, gsq);
  k_go_mfma<<<dim3(8, B_ / 128), TPB, 0, stream>>>(glb1, Wco1t, gsum, gsq, bng_g, bng_b, go);
  k_dadj_mfma<<<BNr / 128, TPB, 0, stream>>>(x2t_bf, Wco2t, go, bco, dadj, bmin, bmax);

  // ---- tadj build (per-b normalize + rowsum) + fused adjacency loss ----
  k_tadj<<<B_, TPB, 0, stream>>>(dadj, bmin, bmax, sadj, out1, tadj_bf, lossa);

  // ---- dynamic GCN ----
  k_fold<1><<<B_ * 8, TPB, 0, stream>>>(x, hT_bf, tadj_bf, xa_bf);
  k_gemm_160<<<1024, TPB, 0, stream>>>(xa_bf, Wtd, hT_bf, 1, ssum2, ssq2);
  k_final<<<(int)(BCN / (4 * TPB)), TPB, 0, stream>>>(hT_bf, out, bn_g, bn_b, ssum2, ssq2, lossa);
}